// Round 1
// 211.731 us; speedup vs baseline: 1.0385x; 1.0385x over previous
//
#include <hip/hip_runtime.h>
#include <hip/hip_bf16.h>

typedef unsigned short u16;
typedef unsigned int u32;
typedef __attribute__((ext_vector_type(4))) float f32x4;
typedef __attribute__((ext_vector_type(8))) __bf16 bf16x8;

constexpr int kDim   = 1024;
constexpr int kSeq   = 2048;
constexpr int kB     = 2;
constexpr int kHeads = 16;
constexpr int kRows  = kB * kSeq;   // 4096

__device__ __forceinline__ u16 f2bf(float f) {
  __hip_bfloat16 h = __float2bfloat16(f);   // HW RNE convert (m240: scalar cast is fine)
  return __builtin_bit_cast(u16, h);
}

__device__ __forceinline__ u32 pkbf(float a, float b) {
  return (u32)f2bf(a) | ((u32)f2bf(b) << 16);
}

__device__ __forceinline__ float exp2x(float x) {
#if __has_builtin(__builtin_amdgcn_exp2f)
  return __builtin_amdgcn_exp2f(x);   // raw v_exp_f32 (we work in log2 domain)
#else
  return exp2f(x);
#endif
}

__device__ __forceinline__ void gload_lds16(const void* src, void* dst) {
  __builtin_amdgcn_global_load_lds(
      (const __attribute__((address_space(1))) void*)src,
      (__attribute__((address_space(3))) void*)dst, 16, 0, 0);
}

__device__ __forceinline__ f32x4 mfma16(bf16x8 a, bf16x8 b, f32x4 c) {
  return __builtin_amdgcn_mfma_f32_16x16x32_bf16(a, b, c, 0, 0, 0);
}

// ---------------- fp32 -> bf16 elementwise convert (vectorized) -------------
__global__ __launch_bounds__(256) void convert_bf16(const float* __restrict__ in,
                                                    u16* __restrict__ out, int n4) {
  int i = blockIdx.x * blockDim.x + threadIdx.x;
  const int stride = gridDim.x * blockDim.x;
  for (; i < n4; i += stride) {
    float4 v = ((const float4*)in)[i];
    ushort4 o;
    o.x = f2bf(v.x); o.y = f2bf(v.y); o.z = f2bf(v.z); o.w = f2bf(v.w);
    ((ushort4*)out)[i] = o;
  }
}

// ---------------- weight transpose: [K,N] f32 -> [N,K] bf16 -----------------
__global__ void transpose_w(const float* __restrict__ in, u16* __restrict__ out,
                            int K, int N) {
  __shared__ float tile[32][33];
  const int tx = threadIdx.x;   // 32
  const int ty = threadIdx.y;   // 8
  const int k0 = blockIdx.y * 32;
  const int n0 = blockIdx.x * 32;
#pragma unroll
  for (int i = 0; i < 4; ++i)
    tile[ty + i * 8][tx] = in[(size_t)(k0 + ty + i * 8) * N + n0 + tx];
  __syncthreads();
#pragma unroll
  for (int i = 0; i < 4; ++i)
    out[(size_t)(n0 + ty + i * 8) * K + k0 + tx] = f2bf(tile[tx][ty + i * 8]);
}

// ---------------- bf16 GEMM: C[M,N] = A[M,K] * Bt[N,K]^T --------------------
// 128x128 tile, BK=64, 4 waves (2x2 of 64x64). LDS XOR-swizzle, source-side.
// EPI: 1 = bf16 * (0.125*log2e) (q)   2 = relu -> bf16   3 = fp32   4 = kv split
template <int EPI>
__global__ __launch_bounds__(256) void gemm_bt(const u16* __restrict__ A,
                                               const u16* __restrict__ Bt,
                                               void* __restrict__ out0,
                                               void* __restrict__ out1, int N) {
  constexpr int K = 1024;
  __shared__ u16 ldsA[128 * 64];
  __shared__ u16 ldsB[128 * 64];
  const int tid  = threadIdx.x;
  const int lane = tid & 63;
  const int wave = tid >> 6;
  const int m0 = blockIdx.y * 128;
  const int n0 = blockIdx.x * 128;
  const int wm = wave >> 1, wn = wave & 1;

  f32x4 acc[4][4];
#pragma unroll
  for (int i = 0; i < 4; ++i)
#pragma unroll
    for (int j = 0; j < 4; ++j) acc[i][j] = (f32x4)0.f;

  const int srow = lane >> 3;  // row within 8-row chunk
  const int sslt = lane & 7;   // 16B slot within row

  for (int kt = 0; kt < K / 64; ++kt) {
    const int k0 = kt * 64;
#pragma unroll
    for (int i = 0; i < 4; ++i) {
      const int c   = wave * 4 + i;      // chunk 0..15, 8 rows each
      const int row = c * 8 + srow;
      const int cb  = sslt ^ (row & 7);  // inverse-swizzled source slot
      gload_lds16(A  + (size_t)(m0 + row) * K + k0 + cb * 8, ldsA + c * 512);
      gload_lds16(Bt + (size_t)(n0 + row) * K + k0 + cb * 8, ldsB + c * 512);
    }
    __syncthreads();
#pragma unroll
    for (int ks = 0; ks < 2; ++ks) {
      const int kb = (ks * 32 + (lane >> 4) * 8) >> 3;  // 16B slot 0..7
      bf16x8 af[4], bfr[4];
#pragma unroll
      for (int mf = 0; mf < 4; ++mf) {
        const int row = wm * 64 + mf * 16 + (lane & 15);
        af[mf] = *(const bf16x8*)(ldsA + row * 64 + (kb ^ (row & 7)) * 8);
      }
#pragma unroll
      for (int nf = 0; nf < 4; ++nf) {
        const int row = wn * 64 + nf * 16 + (lane & 15);
        bfr[nf] = *(const bf16x8*)(ldsB + row * 64 + (kb ^ (row & 7)) * 8);
      }
#pragma unroll
      for (int mf = 0; mf < 4; ++mf)
#pragma unroll
        for (int nf = 0; nf < 4; ++nf)
          acc[mf][nf] = mfma16(af[mf], bfr[nf], acc[mf][nf]);
    }
    __syncthreads();
  }

  const int rb = (lane >> 4) * 4;
  const int cc = lane & 15;
#pragma unroll
  for (int mf = 0; mf < 4; ++mf)
#pragma unroll
    for (int nf = 0; nf < 4; ++nf)
#pragma unroll
      for (int r = 0; r < 4; ++r) {
        const int grow = m0 + wm * 64 + mf * 16 + rb + r;
        const int gcol = n0 + wn * 64 + nf * 16 + cc;
        const float v = acc[mf][nf][r];
        if constexpr (EPI == 1) {
          // 0.125 * log2(e): softmax runs in exp2 domain
          ((u16*)out0)[(size_t)grow * N + gcol] = f2bf(v * 0.18033688f);
        } else if constexpr (EPI == 2) {
          ((u16*)out0)[(size_t)grow * N + gcol] = f2bf(v > 0.f ? v : 0.f);
        } else if constexpr (EPI == 3) {
          ((float*)out0)[(size_t)grow * N + gcol] = v;
        } else {  // EPI == 4: kv split; k cols [0,1024) row-major, v transposed
          const int b = grow >> 11, m = grow & 2047;
          if (gcol < 1024) {
            ((u16*)out0)[(size_t)grow * 1024 + gcol] = f2bf(v);
          } else {
            const int df = gcol - 1024;
            const int h = df >> 6, d = df & 63;
            ((u16*)out1)[(((size_t)(b * kHeads + h) * 64 + d) << 11) + m] = f2bf(v);
          }
        }
      }
}

// ---------------- flash attention (swapped QK^T, in-register softmax) -------
// grid (32 qtiles, 16 heads, 2 batch) = 1024 blocks (4 blocks/CU, 4 waves/SIMD),
// 256 threads = 4 waves x 16 q-rows. Q pre-scaled by 0.125*log2e (exp2 domain).
// S^T = mfma(K_frag, Q_frag): lane holds q = lane&15, kv = 16*nf + 4*(lane>>4)+r.
// Softmax lane-local + 2 shfl_xor, tree reductions, defer-max rescale (T13).
// P^T redistributed to PV B-fragments via shfl (no LDS).
// O^T = mfma(V^T_frag, P^T_frag). K/V double-buffered via global_load_lds.
__global__ __launch_bounds__(256) void attn_kernel(const u16* __restrict__ Q,
                                                   const u16* __restrict__ Kb,
                                                   const u16* __restrict__ Vt,
                                                   u16* __restrict__ O) {
  __shared__ u16 ldsK[2][64 * 64];
  __shared__ u16 ldsV[2][64 * 64];
  const int tid  = threadIdx.x;
  const int lane = tid & 63;
  const int wave = tid >> 6;
  const int b  = blockIdx.z;
  const int h  = blockIdx.y;
  const int q0 = blockIdx.x * 64 + wave * 16;
  const int g    = lane >> 4;   // 4 lane-groups
  const int lq   = lane & 15;   // q column within 16-wide tile

  // Q fragments (used as MFMA B operand): col=q, k=d
  bf16x8 bq[2];
#pragma unroll
  for (int ks = 0; ks < 2; ++ks)
    bq[ks] = *(const bf16x8*)(Q + (size_t)(b * kSeq + q0 + lq) * 1024 +
                              h * 64 + ks * 32 + g * 8);

  f32x4 acc[4];          // O^T: [nd], col=q, row=d
  float m_ = -INFINITY, l_ = 0.f;
#pragma unroll
  for (int nd = 0; nd < 4; ++nd) acc[nd] = (f32x4)0.f;

  const int srow = lane >> 3, sslt = lane & 7;
  const int hiSel = lane & 32;              // nf selector for PV redistribution
  const int src1 = 32 * (g & 1) + lq;       // shfl source lanes
  const int src2 = src1 + 16;

  auto stage = [&](int buf, int kv0) {
#pragma unroll
    for (int i = 0; i < 2; ++i) {
      const int c   = wave * 2 + i;      // 8 chunks of 8 rows
      const int row = c * 8 + srow;
      const int cb  = sslt ^ (row & 7);
      gload_lds16(Kb + (size_t)(b * kSeq + kv0 + row) * 1024 + h * 64 + cb * 8,
                  &ldsK[buf][c * 512]);
      gload_lds16(Vt + (size_t)((b * kHeads + h) * 64 + row) * kSeq + kv0 + cb * 8,
                  &ldsV[buf][c * 512]);
    }
  };

  constexpr int NT = kSeq / 64;
  stage(0, 0);

  for (int t = 0; t < NT; ++t) {
    __syncthreads();                       // drains vmcnt -> buf[cur] ready
    const int cur = t & 1;
    if (t + 1 < NT) stage(cur ^ 1, (t + 1) * 64);

    // ---- S^T = K @ Q^T  (col=q, row=kv) ----
    f32x4 s[4];   // [nf]
#pragma unroll
    for (int nf = 0; nf < 4; ++nf) s[nf] = (f32x4)0.f;
#pragma unroll
    for (int ks = 0; ks < 2; ++ks) {
      const int kb = (ks * 32 + g * 8) >> 3;
      bf16x8 kf[4];
#pragma unroll
      for (int nf = 0; nf < 4; ++nf) {
        const int row = nf * 16 + lq;
        kf[nf] = *(const bf16x8*)(&ldsK[cur][row * 64 + (kb ^ (row & 7)) * 8]);
      }
#pragma unroll
      for (int nf = 0; nf < 4; ++nf)
        s[nf] = mfma16(kf[nf], bq[ks], s[nf]);
    }

    // ---- online softmax (lane-local per q-column, exp2 domain) ----
    // tree max (depth 4 instead of serial 16)
    float a0 = fmaxf(fmaxf(s[0][0], s[0][1]), fmaxf(s[0][2], s[0][3]));
    float a1 = fmaxf(fmaxf(s[1][0], s[1][1]), fmaxf(s[1][2], s[1][3]));
    float a2 = fmaxf(fmaxf(s[2][0], s[2][1]), fmaxf(s[2][2], s[2][3]));
    float a3 = fmaxf(fmaxf(s[3][0], s[3][1]), fmaxf(s[3][2], s[3][3]));
    float mt = fmaxf(fmaxf(a0, a1), fmaxf(a2, a3));
    mt = fmaxf(mt, __shfl_xor(mt, 16));
    mt = fmaxf(mt, __shfl_xor(mt, 32));

    // defer-max (T13): only rescale when the running max grew materially.
    // P bounded by 2^11 otherwise -- fine in bf16/f32.
    if (!__all(mt <= m_ + 11.f)) {
      const float mnew = fmaxf(m_, mt);
      const float sf = exp2x(m_ - mnew);
      m_ = mnew;
      l_ *= sf;
#pragma unroll
      for (int nd = 0; nd < 4; ++nd) acc[nd] *= sf;
    }

    // p = exp2(s - m_); tree sum
    float ts[4];
#pragma unroll
    for (int nf = 0; nf < 4; ++nf) {
#pragma unroll
      for (int r = 0; r < 4; ++r) s[nf][r] = exp2x(s[nf][r] - m_);
      ts[nf] = (s[nf][0] + s[nf][1]) + (s[nf][2] + s[nf][3]);
    }
    float rs = (ts[0] + ts[1]) + (ts[2] + ts[3]);
    rs += __shfl_xor(rs, 16);
    rs += __shfl_xor(rs, 32);
    l_ += rs;

    // pack P^T to bf16 pairs: pk[nf][i] = kv (16nf+4g+2i, +2i+1)
    u32 pk[4][2];
#pragma unroll
    for (int nf = 0; nf < 4; ++nf) {
      pk[nf][0] = pkbf(s[nf][0], s[nf][1]);
      pk[nf][1] = pkbf(s[nf][2], s[nf][3]);
    }
    // redistribute: lane (g,q) needs kv = 32ks+8g..+7 for B-fragment
    bf16x8 pb[2];
#pragma unroll
    for (int ks = 0; ks < 2; ++ks) {
      union { u32 w[4]; bf16x8 v; } u;
#pragma unroll
      for (int i = 0; i < 2; ++i) {
        const int a0s = __shfl((int)pk[2 * ks][i],     src1);
        const int b0s = __shfl((int)pk[2 * ks + 1][i], src1);
        u.w[i] = hiSel ? (u32)b0s : (u32)a0s;
        const int a1s = __shfl((int)pk[2 * ks][i],     src2);
        const int b1s = __shfl((int)pk[2 * ks + 1][i], src2);
        u.w[2 + i] = hiSel ? (u32)b1s : (u32)a1s;
      }
      pb[ks] = u.v;
    }

    // ---- O^T += V^T @ P^T ----
#pragma unroll
    for (int ks = 0; ks < 2; ++ks) {
      const int kb = (ks * 32 + g * 8) >> 3;
      bf16x8 vf[4];
#pragma unroll
      for (int nd = 0; nd < 4; ++nd) {
        const int row = nd * 16 + lq;    // d index into V^T tile
        vf[nd] = *(const bf16x8*)(&ldsV[cur][row * 64 + (kb ^ (row & 7)) * 8]);
      }
#pragma unroll
      for (int nd = 0; nd < 4; ++nd)
        acc[nd] = mfma16(vf[nd], pb[ks], acc[nd]);
    }
  }

  // ---- epilogue: O[q][d] = acc^T / l, packed 8B stores ----
  const float inv = 1.f / l_;
  const size_t rowb = (size_t)(b * kSeq + q0 + lq) * 1024;
#pragma unroll
  for (int nd = 0; nd < 4; ++nd) {
    uint2 o;
    o.x = pkbf(acc[nd][0] * inv, acc[nd][1] * inv);
    o.y = pkbf(acc[nd][2] * inv, acc[nd][3] * inv);
    *(uint2*)(O + rowb + h * 64 + nd * 16 + g * 4) = o;
  }
}

// ---------------- in-place LayerNorm over last dim (1024) -------------------
__global__ __launch_bounds__(256) void ln_kernel(float* __restrict__ io,
                                                 const float* __restrict__ gamma) {
  const int row = blockIdx.x;
  float* p = io + (size_t)row * 1024;
  float4 v = ((const float4*)p)[threadIdx.x];
  float s  = v.x + v.y + v.z + v.w;
  float ss = v.x * v.x + v.y * v.y + v.z * v.z + v.w * v.w;
#pragma unroll
  for (int m = 1; m < 64; m <<= 1) {
    s  += __shfl_xor(s, m);
    ss += __shfl_xor(ss, m);
  }
  __shared__ float red[8];
  const int wave = threadIdx.x >> 6, lane = threadIdx.x & 63;
  if (lane == 0) { red[wave] = s; red[4 + wave] = ss; }
  __syncthreads();
  s  = red[0] + red[1] + red[2] + red[3];
  ss = red[4] + red[5] + red[6] + red[7];
  const float mean = s * (1.f / 1024.f);
  const float var  = ss * (1.f / 1024.f) - mean * mean;
  const float rr   = rsqrtf(var + 1e-5f);
  float4 g = ((const float4*)gamma)[threadIdx.x];
  v.x = (v.x - mean) * rr * g.x;
  v.y = (v.y - mean) * rr * g.y;
  v.z = (v.z - mean) * rr * g.z;
  v.w = (v.w - mean) * rr * g.w;
  ((float4*)p)[threadIdx.x] = v;
}

// ---------------------------------------------------------------------------
extern "C" void kernel_launch(void* const* d_in, const int* in_sizes, int n_in,
                              void* d_out, int out_size, void* d_ws, size_t ws_size,
                              hipStream_t stream) {
  const float* x      = (const float*)d_in[0];
  const float* ctx    = (const float*)d_in[1];
  const float* w_kv   = (const float*)d_in[2];
  const float* w_q    = (const float*)d_in[3];
  const float* w_out1 = (const float*)d_in[4];
  const float* w_out2 = (const float*)d_in[5];
  const float* gamma  = (const float*)d_in[6];

  char* ws = (char*)d_ws;
  size_t off = 0;
  auto alloc = [&](size_t bytes) {
    void* p = ws + off;
    off += (bytes + 255) & ~(size_t)255;
    return p;
  };
  u16* xb   = (u16*)alloc((size_t)kRows * 1024 * 2);
  u16* cb   = (u16*)alloc((size_t)kRows * 1024 * 2);
  u16* wkvT = (u16*)alloc((size_t)2048 * 1024 * 2);
  u16* wqT  = (u16*)alloc((size_t)1024 * 1024 * 2);
  u16* w1T  = (u16*)alloc((size_t)1024 * 1024 * 2);
  u16* w2T  = (u16*)alloc((size_t)1024 * 1024 * 2);
  u16* kbuf = (u16*)alloc((size_t)kRows * 1024 * 2);
  u16* vT   = (u16*)alloc((size_t)kRows * 1024 * 2);
  u16* qbuf = (u16*)alloc((size_t)kRows * 1024 * 2);
  u16* attno  = cb;  // ctx-bf16 dead after kv GEMM; attention output reuses it
  u16* hidden = xb;  // x-bf16 dead after q GEMM; MLP hidden reuses it

  convert_bf16<<<1024, 256, 0, stream>>>(x, xb, kRows * 1024 / 4);
  convert_bf16<<<1024, 256, 0, stream>>>(ctx, cb, kRows * 1024 / 4);

  dim3 tb(32, 8);
  transpose_w<<<dim3(2048 / 32, 1024 / 32), tb, 0, stream>>>(w_kv, wkvT, 1024, 2048);
  transpose_w<<<dim3(1024 / 32, 1024 / 32), tb, 0, stream>>>(w_q, wqT, 1024, 1024);
  transpose_w<<<dim3(1024 / 32, 1024 / 32), tb, 0, stream>>>(w_out1, w1T, 1024, 1024);
  transpose_w<<<dim3(1024 / 32, 1024 / 32), tb, 0, stream>>>(w_out2, w2T, 1024, 1024);

  // kv = ctx @ w_kv -> k [b,m,1024] + v^T [b,h,64,m]
  gemm_bt<4><<<dim3(2048 / 128, kRows / 128), 256, 0, stream>>>(cb, wkvT, kbuf, vT, 2048);
  // q = (x @ w_q) * 0.125 * log2e
  gemm_bt<1><<<dim3(1024 / 128, kRows / 128), 256, 0, stream>>>(xb, wqT, qbuf, nullptr, 1024);
  // attention
  attn_kernel<<<dim3(kSeq / 64, kHeads, kB), 256, 0, stream>>>(qbuf, kbuf, vT, attno);
  // hidden = relu(attno @ w_out1)
  gemm_bt<2><<<dim3(1024 / 128, kRows / 128), 256, 0, stream>>>(attno, w1T, hidden, nullptr, 1024);
  // out = hidden @ w_out2 (fp32)
  gemm_bt<3><<<dim3(1024 / 128, kRows / 128), 256, 0, stream>>>(hidden, w2T, d_out, nullptr, 1024);
  // in-place LayerNorm
  ln_kernel<<<kRows, 256, 0, stream>>>((float*)d_out, gamma);
}